// Round 1
// baseline (261.381 us; speedup 1.0000x reference)
//
#include <hip/hip_runtime.h>
#include <hip/hip_bf16.h>
#include <stdint.h>

#define H 128
#define NE 500000

typedef __bf16 bf16x8 __attribute__((ext_vector_type(8)));
typedef float f32x4 __attribute__((ext_vector_type(4)));

__device__ __forceinline__ float fast_silu(float x) {
    // silu(x) = x / (1 + exp(-x));  exp(-x) = exp2(-x * log2(e))
    float e = __builtin_amdgcn_exp2f(x * -1.44269504088896341f);
    return x * __builtin_amdgcn_rcpf(1.0f + e);
}

__device__ __forceinline__ unsigned f2bf(float f) {
    // round-to-nearest-even f32 -> bf16 (as u16 in low bits)
    unsigned u = __builtin_bit_cast(unsigned, f);
    return (u + 0x7FFFu + ((u >> 16) & 1u)) >> 16;
}

// ---------------------------------------------------------------------------
// Prep: P1[r][c] = emb[r] @ w_lin[0:128][c] + b_lin[c]
//       P2[r][c] = emb[r] @ w_lin[128:256][c]
//       w3t[c][k] = bf16(w_lin[256+k][c])   (transposed, bf16-pair packed)
// grid = 95 + 32 = 127 blocks x 256 threads
// ---------------------------------------------------------------------------
__global__ void prep_kernel(const float* __restrict__ emb,
                            const float* __restrict__ w_lin,
                            const float* __restrict__ b_lin,
                            float* __restrict__ P1, float* __restrict__ P2,
                            unsigned* __restrict__ w3t) {
    int b = blockIdx.x, t = threadIdx.x;
    if (b < 95) {
        int c = t & (H - 1);
        int half = t >> 7;                 // 0 -> P1, 1 -> P2
        const float* wb = w_lin + half * (H * H);
        float a = half ? 0.0f : b_lin[c];
        #pragma unroll 4
        for (int k = 0; k < H; ++k)
            a = fmaf(emb[b * H + k], wb[k * H + c], a);
        (half ? P2 : P1)[b * H + c] = a;
    } else {
        int idx = (b - 95) * 256 + t;      // 0..8191 ; row c = idx>>6, k-pair = idx&63
        int c = idx >> 6;
        int k = (idx & 63) * 2;
        unsigned lo = f2bf(w_lin[(2 * H + k) * H + c]);
        unsigned hi = f2bf(w_lin[(2 * H + k + 1) * H + c]);
        w3t[idx] = lo | (hi << 16);
    }
}

// ---------------------------------------------------------------------------
// Main: per block = 128 edges x 128 outputs.
//   h[e][c] = silu(rbf[e] @ w_rbf[:,c] + b_rbf[c])  -> LDS (bf16, XOR-swizzled)
//   acc = h @ W3 (bf16 MFMA 16x16x32, K=128)
//   out = silu(acc + P1[x[i]] + P2[x[j]])
// 4 waves in 2x2 grid: wave handles 64 edges x 64 cols.
// ---------------------------------------------------------------------------
__global__ __launch_bounds__(256, 2)
void edge_kernel(const float* __restrict__ rbf,
                 const int* __restrict__ ei, const int* __restrict__ ej,
                 const int* __restrict__ xin,
                 const float* __restrict__ w_rbf, const float* __restrict__ b_rbf,
                 const float* __restrict__ P1, const float* __restrict__ P2,
                 const unsigned* __restrict__ w3t,
                 float* __restrict__ out) {
    __shared__ unsigned h_u[H * 64];   // 128 rows x 256 B (bf16[128][128], swizzled)
    __shared__ unsigned w_u[H * 64];   // W3^T, 128 rows (c) x 256 B, swizzled
    __shared__ int xi_s[128];
    __shared__ int xj_s[128];
    char* hs = (char*)h_u;
    char* wsm = (char*)w_u;

    const int tid = threadIdx.x;
    const int e0 = blockIdx.x * 128;

    // ---- stage W3^T into LDS (swizzle: byte ^= (row&7)<<4) ----
    #pragma unroll 8
    for (int it = 0; it < 32; ++it) {
        int idx = tid + it * 256;          // 0..8191
        int c = idx >> 6;
        int boff = (idx & 63) * 4;
        *(unsigned*)(wsm + c * 256 + (boff ^ ((c & 7) << 4))) = w3t[idx];
    }

    // ---- per-edge node-embedding indices ----
    if (tid < 128) {
        int e = e0 + tid;
        int a = 0, b = 0;
        if (e < NE) { a = xin[ei[e]]; b = xin[ej[e]]; }
        xi_s[tid] = a;
        xj_s[tid] = b;
    }

    // ---- produce h tile: thread owns cols (c2, c2+1), rows strided by 4 ----
    {
        const int c2 = (tid & 63) * 2;
        float wk0[6], wk1[6];
        #pragma unroll
        for (int k = 0; k < 6; ++k) {
            float2 t2 = *(const float2*)(w_rbf + k * H + c2);
            wk0[k] = t2.x; wk1[k] = t2.y;
        }
        float2 bb = *(const float2*)(b_rbf + c2);
        const int er0 = tid >> 6;
        #pragma unroll 4
        for (int it = 0; it < 32; ++it) {
            int el = er0 + it * 4;
            int e = e0 + el;
            float r0 = 0.f, r1 = 0.f, r2 = 0.f, r3 = 0.f, r4 = 0.f, r5 = 0.f;
            if (e < NE) {
                const float* rp = rbf + e * 6;
                float2 p0 = *(const float2*)(rp);
                float2 p1 = *(const float2*)(rp + 2);
                float2 p2 = *(const float2*)(rp + 4);
                r0 = p0.x; r1 = p0.y; r2 = p1.x; r3 = p1.y; r4 = p2.x; r5 = p2.y;
            }
            float s0 = bb.x, s1 = bb.y;
            s0 = fmaf(r0, wk0[0], s0); s1 = fmaf(r0, wk1[0], s1);
            s0 = fmaf(r1, wk0[1], s0); s1 = fmaf(r1, wk1[1], s1);
            s0 = fmaf(r2, wk0[2], s0); s1 = fmaf(r2, wk1[2], s1);
            s0 = fmaf(r3, wk0[3], s0); s1 = fmaf(r3, wk1[3], s1);
            s0 = fmaf(r4, wk0[4], s0); s1 = fmaf(r4, wk1[4], s1);
            s0 = fmaf(r5, wk0[5], s0); s1 = fmaf(r5, wk1[5], s1);
            unsigned pv = f2bf(fast_silu(s0)) | (f2bf(fast_silu(s1)) << 16);
            *(unsigned*)(hs + el * 256 + ((c2 * 2) ^ ((el & 7) << 4))) = pv;
        }
    }
    __syncthreads();

    // ---- MFMA: wave (we, wc) owns edges [we*64, +64) x cols [wc*64, +64) ----
    const int wave = tid >> 6;
    const int lane = tid & 63;
    const int we = wave >> 1;
    const int wc = wave & 1;
    const int l15 = lane & 15;
    const int lq = lane >> 4;     // 0..3

    f32x4 acc[4][4];
    #pragma unroll
    for (int a = 0; a < 4; ++a)
        #pragma unroll
        for (int b = 0; b < 4; ++b)
            acc[a][b] = (f32x4){0.f, 0.f, 0.f, 0.f};

    #pragma unroll
    for (int ks = 0; ks < 4; ++ks) {
        const int kbyte = (ks * 32 + lq * 8) * 2;   // 16B-aligned within row
        bf16x8 afrag[4], bfrag[4];
        #pragma unroll
        for (int ef = 0; ef < 4; ++ef) {
            int row = we * 64 + ef * 16 + l15;
            afrag[ef] = *(const bf16x8*)(hs + row * 256 + (kbyte ^ ((row & 7) << 4)));
        }
        #pragma unroll
        for (int cf = 0; cf < 4; ++cf) {
            int row = wc * 64 + cf * 16 + l15;
            bfrag[cf] = *(const bf16x8*)(wsm + row * 256 + (kbyte ^ ((row & 7) << 4)));
        }
        #pragma unroll
        for (int ef = 0; ef < 4; ++ef)
            #pragma unroll
            for (int cf = 0; cf < 4; ++cf)
                acc[ef][cf] = __builtin_amdgcn_mfma_f32_16x16x32_bf16(
                    afrag[ef], bfrag[cf], acc[ef][cf], 0, 0, 0);
    }

    // ---- epilogue: out[e][c] = silu(acc + P1[xi][c] + P2[xj][c]) ----
    #pragma unroll
    for (int ef = 0; ef < 4; ++ef) {
        const int el_base = we * 64 + ef * 16 + lq * 4;
        #pragma unroll
        for (int cf = 0; cf < 4; ++cf) {
            const int c = wc * 64 + cf * 16 + l15;
            #pragma unroll
            for (int r = 0; r < 4; ++r) {
                int el = el_base + r;
                int e = e0 + el;
                if (e < NE) {
                    float v = acc[ef][cf][r]
                            + P1[xi_s[el] * H + c]
                            + P2[xj_s[el] * H + c];
                    out[(size_t)e * H + c] = fast_silu(v);
                }
            }
        }
    }
}

extern "C" void kernel_launch(void* const* d_in, const int* in_sizes, int n_in,
                              void* d_out, int out_size, void* d_ws, size_t ws_size,
                              hipStream_t stream) {
    const int*   x      = (const int*)d_in[0];
    const float* rbf    = (const float*)d_in[1];
    const int*   ei     = (const int*)d_in[2];
    const int*   ej     = (const int*)d_in[3];
    const float* emb    = (const float*)d_in[4];
    const float* w_rbf  = (const float*)d_in[5];
    const float* b_rbf  = (const float*)d_in[6];
    const float* w_lin  = (const float*)d_in[7];
    const float* b_lin  = (const float*)d_in[8];
    float* out = (float*)d_out;

    float*    P1  = (float*)d_ws;                 // 95*128 f32
    float*    P2  = P1 + 95 * H;                  // 95*128 f32
    unsigned* w3t = (unsigned*)(P2 + 95 * H);     // 128*64 u32 (bf16 pairs)

    prep_kernel<<<95 + 32, 256, 0, stream>>>(emb, w_lin, b_lin, P1, P2, w3t);

    int nblk = (NE + 127) / 128;                  // 3907
    edge_kernel<<<nblk, 256, 0, stream>>>(rbf, ei, ej, x, w_rbf, b_rbf,
                                          P1, P2, w3t, out);
}

// Round 2
// 134.442 us; speedup vs baseline: 1.9442x; 1.9442x over previous
//
#include <hip/hip_runtime.h>
#include <hip/hip_bf16.h>
#include <stdint.h>

#define H 128
#define NE 500000

typedef __bf16 bf16x8 __attribute__((ext_vector_type(8)));
typedef float f32x4 __attribute__((ext_vector_type(4)));

__device__ __forceinline__ float fast_silu(float x) {
    float e = __builtin_amdgcn_exp2f(x * -1.44269504088896341f);
    return x * __builtin_amdgcn_rcpf(1.0f + e);
}

__device__ __forceinline__ unsigned f2bf(float f) {
    unsigned u = __builtin_bit_cast(unsigned, f);
    return (u + 0x7FFFu + ((u >> 16) & 1u)) >> 16;
}

// ---------------------------------------------------------------------------
// Prep: P1[r][c] = emb[r] @ w_lin[0:128][c] + b_lin[c]
//       P2[r][c] = emb[r] @ w_lin[128:256][c]
//       w3t[c][k] = bf16(w_lin[256+k][c])   (transposed, bf16-pair packed)
// ---------------------------------------------------------------------------
__global__ void prep_kernel(const float* __restrict__ emb,
                            const float* __restrict__ w_lin,
                            const float* __restrict__ b_lin,
                            float* __restrict__ P1, float* __restrict__ P2,
                            unsigned* __restrict__ w3t) {
    int b = blockIdx.x, t = threadIdx.x;
    if (b < 95) {
        int c = t & (H - 1);
        int half = t >> 7;
        const float* wb = w_lin + half * (H * H);
        float a = half ? 0.0f : b_lin[c];
        #pragma unroll 4
        for (int k = 0; k < H; ++k)
            a = fmaf(emb[b * H + k], wb[k * H + c], a);
        (half ? P2 : P1)[b * H + c] = a;
    } else {
        int idx = (b - 95) * 256 + t;      // row c = idx>>6, k-pair = idx&63
        int c = idx >> 6;
        int k = (idx & 63) * 2;
        unsigned lo = f2bf(w_lin[(2 * H + k) * H + c]);
        unsigned hi = f2bf(w_lin[(2 * H + k + 1) * H + c]);
        w3t[idx] = lo | (hi << 16);
    }
}

// ---------------------------------------------------------------------------
// Main: 128 edges x 128 outputs per block, 4 waves (2 edge x 2 col).
//   acc = mfma(W3^T frag, h frag)  -> out^T fragment layout:
//   lane holds 4 CONSECUTIVE cols for one edge -> float4 stores/loads.
// ---------------------------------------------------------------------------
__global__ __launch_bounds__(256, 3)
void edge_kernel(const float* __restrict__ rbf,
                 const int* __restrict__ ei, const int* __restrict__ ej,
                 const int* __restrict__ xin,
                 const float* __restrict__ w_rbf, const float* __restrict__ b_rbf,
                 const float* __restrict__ P1, const float* __restrict__ P2,
                 const unsigned* __restrict__ w3t,
                 float* __restrict__ out) {
    __shared__ char hs[H * 256];        // bf16 h[128][128], XOR-swizzled, 32KB
    __shared__ float rbf_s[128 * 8];    // rbf padded to 8 f32/edge, 4KB
    __shared__ int xi_s[128];
    __shared__ int xj_s[128];

    const int tid = threadIdx.x;
    const int e0 = blockIdx.x * 128;

    // ---- stage rbf -> LDS, coalesced (3 dwords/thread) ----
    const int gbase = e0 * 6;
    #pragma unroll
    for (int k = 0; k < 3; ++k) {
        int d = tid + k * 256;                 // 0..767
        float v = 0.0f;
        if (gbase + d < NE * 6) v = rbf[gbase + d];
        rbf_s[(d / 6) * 8 + (d % 6)] = v;
    }

    // ---- per-edge node-embedding indices ----
    if (tid < 128) {
        int e = e0 + tid;
        int a = 0, b = 0;
        if (e < NE) { a = xin[ei[e]]; b = xin[ej[e]]; }
        xi_s[tid] = a;
        xj_s[tid] = b;
    }
    __syncthreads();

    // ---- h-phase: thread owns 8 cols x 8 edges ----
    {
        const int c8 = (tid & 15) * 8;
        const int eg = tid >> 4;
        f32x4 w0[6], w1[6];
        #pragma unroll
        for (int k = 0; k < 6; ++k) {
            w0[k] = *(const f32x4*)(w_rbf + k * H + c8);
            w1[k] = *(const f32x4*)(w_rbf + k * H + c8 + 4);
        }
        f32x4 b0 = *(const f32x4*)(b_rbf + c8);
        f32x4 b1 = *(const f32x4*)(b_rbf + c8 + 4);

        #pragma unroll
        for (int i = 0; i < 8; ++i) {
            int el = eg * 8 + i;
            f32x4 r03 = *(const f32x4*)(rbf_s + el * 8);
            float2 r45 = *(const float2*)(rbf_s + el * 8 + 4);
            float rk[6] = {r03[0], r03[1], r03[2], r03[3], r45.x, r45.y};
            f32x4 s0 = b0, s1 = b1;
            #pragma unroll
            for (int k = 0; k < 6; ++k) {
                s0 += rk[k] * w0[k];
                s1 += rk[k] * w1[k];
            }
            unsigned p0 = f2bf(fast_silu(s0[0])) | (f2bf(fast_silu(s0[1])) << 16);
            unsigned p1 = f2bf(fast_silu(s0[2])) | (f2bf(fast_silu(s0[3])) << 16);
            unsigned p2 = f2bf(fast_silu(s1[0])) | (f2bf(fast_silu(s1[1])) << 16);
            unsigned p3 = f2bf(fast_silu(s1[2])) | (f2bf(fast_silu(s1[3])) << 16);
            uint4 pv = {p0, p1, p2, p3};
            *(uint4*)(hs + el * 256 + ((c8 * 2) ^ ((el & 15) << 4))) = pv;
        }
    }

    // ---- W3^T fragments: registers, straight from L2 (no LDS) ----
    const int wave = tid >> 6;
    const int lane = tid & 63;
    const int we = wave >> 1;
    const int wc = wave & 1;
    const int l15 = lane & 15;
    const int lq = lane >> 4;

    bf16x8 bfr[4][4];   // [cf][ks]
    #pragma unroll
    for (int cf = 0; cf < 4; ++cf) {
        int c = wc * 64 + cf * 16 + l15;
        #pragma unroll
        for (int ks = 0; ks < 4; ++ks)
            bfr[cf][ks] = *(const bf16x8*)((const char*)w3t + c * 256 + ks * 64 + lq * 16);
    }
    __syncthreads();

    // ---- MFMA: acc[ef][cf] = W3^T(frag cf) x h^T(frag ef) = out^T tile ----
    f32x4 acc[4][4];
    #pragma unroll
    for (int a = 0; a < 4; ++a)
        #pragma unroll
        for (int b = 0; b < 4; ++b)
            acc[a][b] = (f32x4){0.f, 0.f, 0.f, 0.f};

    #pragma unroll
    for (int ks = 0; ks < 4; ++ks) {
        const int kb = ks * 64 + lq * 16;
        bf16x8 afr[4];
        #pragma unroll
        for (int ef = 0; ef < 4; ++ef) {
            int row = we * 64 + ef * 16 + l15;
            afr[ef] = *(const bf16x8*)(hs + row * 256 + (kb ^ ((row & 15) << 4)));
        }
        #pragma unroll
        for (int ef = 0; ef < 4; ++ef)
            #pragma unroll
            for (int cf = 0; cf < 4; ++cf)
                acc[ef][cf] = __builtin_amdgcn_mfma_f32_16x16x32_bf16(
                    bfr[cf][ks], afr[ef], acc[ef][cf], 0, 0, 0);
    }

    // ---- epilogue: lane holds 4 consecutive cols for one edge -> float4 ----
    #pragma unroll
    for (int ef = 0; ef < 4; ++ef) {
        const int el = we * 64 + ef * 16 + l15;
        const int e = e0 + el;
        if (e < NE) {
            const float* p1 = P1 + xi_s[el] * H;
            const float* p2 = P2 + xj_s[el] * H;
            float* op = out + (size_t)e * H;
            #pragma unroll
            for (int cf = 0; cf < 4; ++cf) {
                const int cb = wc * 64 + cf * 16 + lq * 4;
                f32x4 q1 = *(const f32x4*)(p1 + cb);
                f32x4 q2 = *(const f32x4*)(p2 + cb);
                f32x4 o;
                #pragma unroll
                for (int r = 0; r < 4; ++r)
                    o[r] = fast_silu(acc[ef][cf][r] + q1[r] + q2[r]);
                *(f32x4*)(op + cb) = o;
            }
        }
    }
}

extern "C" void kernel_launch(void* const* d_in, const int* in_sizes, int n_in,
                              void* d_out, int out_size, void* d_ws, size_t ws_size,
                              hipStream_t stream) {
    const int*   x      = (const int*)d_in[0];
    const float* rbf    = (const float*)d_in[1];
    const int*   ei     = (const int*)d_in[2];
    const int*   ej     = (const int*)d_in[3];
    const float* emb    = (const float*)d_in[4];
    const float* w_rbf  = (const float*)d_in[5];
    const float* b_rbf  = (const float*)d_in[6];
    const float* w_lin  = (const float*)d_in[7];
    const float* b_lin  = (const float*)d_in[8];
    float* out = (float*)d_out;

    float*    P1  = (float*)d_ws;                 // 95*128 f32
    float*    P2  = P1 + 95 * H;                  // 95*128 f32
    unsigned* w3t = (unsigned*)(P2 + 95 * H);     // 128*64 u32 (bf16 pairs)

    prep_kernel<<<95 + 32, 256, 0, stream>>>(emb, w_lin, b_lin, P1, P2, w3t);

    int nblk = (NE + 127) / 128;                  // 3907
    edge_kernel<<<nblk, 256, 0, stream>>>(rbf, ei, ej, x, w_rbf, b_rbf,
                                          P1, P2, w3t, out);
}